// Round 3
// baseline (2116.838 us; speedup 1.0000x reference)
//
#include <hip/hip_runtime.h>

// ---------------------------------------------------------------------------
// GCN: 4x GCNConv(128->128) + final linear.
// CSR build with zero global atomics (two-level counting sort).
// Per layer: MFMA GEMM t' = disq*(h@W) (W split hi/lo bf16; h bf16 from
// layer 1 on), then CSR gather-aggregate (separate kernel — fusion regressed:
// aggregate is MLP/latency-bound and needs max blocks + deep pipelines).
// Aggregate: 16-lane quarter OWNS one node, 8-deep rotating gather pipeline
// (32 outstanding 16B loads/wave), edges[] carries pre-multiplied byte offs.
// ---------------------------------------------------------------------------

#define SCAN_CHUNK 1024
#define NBUCK_MAX  512
#define BCAP       6144

typedef __attribute__((ext_vector_type(8))) short bf16x8;
typedef __attribute__((ext_vector_type(4))) float f32x4;

__device__ inline unsigned bf16pack(float a, float b) {  // RTNE pack, a->low
    unsigned ua = __float_as_uint(a);
    unsigned ub = __float_as_uint(b);
    ua = (ua + 0x7fffu + ((ua >> 16) & 1u)) >> 16;
    ub = (ub + 0x7fffu + ((ub >> 16) & 1u)) & 0xffff0000u;
    return ua | ub;
}

__device__ inline void split2(float x, ushort& hi, ushort& lo) {
    unsigned u = __float_as_uint(x);
    unsigned r = (u + 0x7fffu + ((u >> 16) & 1u)) & 0xffff0000u;
    hi = (ushort)(r >> 16);
    float rem = x - __uint_as_float(r);
    unsigned u2 = __float_as_uint(rem);
    lo = (ushort)((u2 + 0x7fffu + ((u2 >> 16) & 1u)) >> 16);
}

__device__ inline void bf16x8_expand(uint4 w, float4& a, float4& b) {
    a.x = __uint_as_float(w.x << 16);
    a.y = __uint_as_float(w.x & 0xffff0000u);
    a.z = __uint_as_float(w.y << 16);
    a.w = __uint_as_float(w.y & 0xffff0000u);
    b.x = __uint_as_float(w.z << 16);
    b.y = __uint_as_float(w.z & 0xffff0000u);
    b.z = __uint_as_float(w.w << 16);
    b.w = __uint_as_float(w.w & 0xffff0000u);
}

// ---- W prep: transpose + hi/lo bf16 split of 5 weight matrices ----
__global__ __launch_bounds__(256) void k_prepw(const float* W0, const float* W1,
                                               const float* W2, const float* W3,
                                               const float* W4,
                                               ushort* __restrict__ hiO,
                                               ushort* __restrict__ loO) {
    const float* W = (blockIdx.x == 0) ? W0 : (blockIdx.x == 1) ? W1 :
                     (blockIdx.x == 2) ? W2 : (blockIdx.x == 3) ? W3 : W4;
    ushort* h = hiO + (size_t)blockIdx.x * 16384;
    ushort* l = loO + (size_t)blockIdx.x * 16384;
    for (int idx = threadIdx.x; idx < 4096; idx += 256) {
        int n  = idx >> 5;
        int kq = (idx & 31) * 4;
        ushort hs[4], ls[4];
#pragma unroll
        for (int j = 0; j < 4; j++) split2(W[(kq + j) * 128 + n], hs[j], ls[j]);
        *(uint2*)&h[n * 128 + kq] =
            make_uint2(hs[0] | ((unsigned)hs[1] << 16), hs[2] | ((unsigned)hs[3] << 16));
        *(uint2*)&l[n * 128 + kq] =
            make_uint2(ls[0] | ((unsigned)ls[1] << 16), ls[2] | ((unsigned)ls[3] << 16));
    }
}

// ---- Level-1 pass A: per-block bucket histogram. hist laid out [K][B1]. ----
__global__ __launch_bounds__(256) void k_hist(const int* __restrict__ col,
                                              int* __restrict__ hist,
                                              int E, int K, int B1, int chunk) {
    __shared__ int cnt[NBUCK_MAX];
    int b = blockIdx.x, t = threadIdx.x;
    for (int k = t; k < K; k += 256) cnt[k] = 0;
    __syncthreads();
    int e0 = b * chunk, e1 = min(e0 + chunk, E);
    for (int e = e0 + t; e < e1; e += 256) atomicAdd(&cnt[col[e] >> 8], 1);
    __syncthreads();
    for (int k = t; k < K; k += 256) hist[k * B1 + b] = cnt[k];
}

// ---- 3-phase multi-block exclusive scan ----
__global__ __launch_bounds__(256) void k_scan_part(const int* __restrict__ count,
                                                   int* __restrict__ partials, int n) {
    __shared__ int red[256];
    int t = threadIdx.x;
    int base = blockIdx.x * SCAN_CHUNK + t * 4;
    int s = 0;
#pragma unroll
    for (int j = 0; j < 4; j++) {
        int i = base + j;
        if (i < n) s += count[i];
    }
    red[t] = s;
    __syncthreads();
    for (int off = 128; off > 0; off >>= 1) {
        if (t < off) red[t] += red[t + off];
        __syncthreads();
    }
    if (t == 0) partials[blockIdx.x] = red[0];
}

__global__ __launch_bounds__(1024) void k_scan_top(const int* __restrict__ partials,
                                                   int* __restrict__ blockOff,
                                                   int* __restrict__ result,
                                                   int nb, int n) {
    __shared__ int sums[1024];
    int t = threadIdx.x;
    int v = (t < nb) ? partials[t] : 0;
    sums[t] = v;
    __syncthreads();
    for (int off = 1; off < 1024; off <<= 1) {
        int u = (t >= off) ? sums[t - off] : 0;
        __syncthreads();
        sums[t] += u;
        __syncthreads();
    }
    if (t < nb) blockOff[t] = sums[t] - v;
    if (t == nb - 1) result[n] = sums[t];
}

__global__ __launch_bounds__(256) void k_scan_out(const int* __restrict__ count,
                                                  const int* __restrict__ blockOff,
                                                  int* __restrict__ result, int n) {
    __shared__ int sums[256];
    int t = threadIdx.x;
    int base = blockIdx.x * SCAN_CHUNK + t * 4;
    int c[4]; int s = 0;
#pragma unroll
    for (int j = 0; j < 4; j++) {
        int i = base + j;
        c[j] = (i < n) ? count[i] : 0;
        s += c[j];
    }
    sums[t] = s;
    __syncthreads();
    for (int off = 1; off < 256; off <<= 1) {
        int u = (t >= off) ? sums[t - off] : 0;
        __syncthreads();
        sums[t] += u;
        __syncthreads();
    }
    int run = blockOff[blockIdx.x] + sums[t] - s;
#pragma unroll
    for (int j = 0; j < 4; j++) {
        int i = base + j;
        if (i < n) result[i] = run;
        run += c[j];
    }
}

// ---- Level-1 pass B: scatter edges into bucket-grouped order. ----
__global__ __launch_bounds__(256) void k_scatter(const int* __restrict__ row,
                                                 const int* __restrict__ col,
                                                 const float* __restrict__ ew,
                                                 const int* __restrict__ binBase,
                                                 uint2* __restrict__ etmp,
                                                 int E, int K, int B1, int chunk) {
    __shared__ int cur[NBUCK_MAX];
    int b = blockIdx.x, t = threadIdx.x;
    for (int k = t; k < K; k += 256) cur[k] = binBase[k * B1 + b];
    __syncthreads();
    int e0 = b * chunk, e1 = min(e0 + chunk, E);
    for (int e = e0 + t; e < e1; e += 256) {
        int c = col[e];
        int k = c >> 8;
        int pos = atomicAdd(&cur[k], 1);
        etmp[pos] = make_uint2((unsigned)row[e] | ((unsigned)(c & 255) << 24),
                               __float_as_uint(ew[e]));
    }
}

// ---- Level-2: per-bucket in-LDS counting sort; emit edges/offsets/disq. ----
// edges[].x = src * 256 (pre-multiplied byte offset into the bf16 t' matrix).
__global__ __launch_bounds__(256) void k_bucket(const uint2* __restrict__ etmp,
                                                const int* __restrict__ binBase,
                                                uint2* __restrict__ edges,
                                                int* __restrict__ offsets,
                                                float* __restrict__ disq,
                                                int N, int K, int B1) {
    __shared__ unsigned ls[BCAP];
    __shared__ unsigned lw[BCAP];
    __shared__ int   cnt[256];
    __shared__ float sew[256];
    __shared__ int   excl[257];
    int k = blockIdx.x, t = threadIdx.x;
    int bStart = binBase[k * B1];
    int bEnd   = binBase[(k + 1) * B1];
    int size   = bEnd - bStart;
    cnt[t] = 0; sew[t] = 0.f;
    __syncthreads();
    for (int i = t; i < size && i < BCAP; i += 256) {
        uint2 m = etmp[bStart + i];
        ls[i] = m.x; lw[i] = m.y;
        int j = m.x >> 24;
        atomicAdd(&cnt[j], 1);
        atomicAdd(&sew[j], __uint_as_float(m.y));
    }
    __syncthreads();
    excl[t + 1] = cnt[t];
    if (t == 0) excl[0] = 0;
    __syncthreads();
    for (int off = 1; off < 256; off <<= 1) {
        int add = (t + 1 > off) ? excl[t + 1 - off] : 0;
        __syncthreads();
        excl[t + 1] += add;
        __syncthreads();
    }
    int node = (k << 8) + t;
    if (node < N) {
        offsets[node] = bStart + excl[t];
        disq[node]    = rsqrtf(1.0f + sew[t]);
    }
    if (k == K - 1 && t == 0) offsets[N] = bEnd;
    cnt[t] = excl[t];
    __syncthreads();
    for (int i = t; i < size && i < BCAP; i += 256) {
        unsigned s = ls[i];
        int j = s >> 24;
        int pos = atomicAdd(&cnt[j], 1);
        edges[bStart + pos] = make_uint2((s & 0x00FFFFFFu) << 8, lw[i]);
    }
}

// ---- MFMA GEMM, fp32 A (layer 0 only): split A hi/lo, 3 MFMAs/frag. ----
// D = W^T * h^T; C/D col=node, row=feature quad -> packed bf16 stores.
__global__ __launch_bounds__(256) void k_gemm_f32A(const float* __restrict__ A,
                                                   const ushort* __restrict__ WThi,
                                                   const ushort* __restrict__ WTlo,
                                                   const float* __restrict__ disq,
                                                   unsigned* __restrict__ Cout, int N) {
    __shared__ ushort Whi_s[128][136];
    __shared__ ushort Wlo_s[128][136];
    int tid = threadIdx.x;
#pragma unroll
    for (int r = 0; r < 8; r++) {
        int n  = r * 16 + (tid >> 4);
        int kq = (tid & 15) * 8;
        *(uint4*)&Whi_s[n][kq] = *(const uint4*)&WThi[n * 128 + kq];
        *(uint4*)&Wlo_s[n][kq] = *(const uint4*)&WTlo[n * 128 + kq];
    }
    __syncthreads();

    int wv = tid >> 6, ln = tid & 63;
    int quad = ln >> 4, col = ln & 15;
    int nodeBase = blockIdx.x * 128 + wv * 32;
    int node0 = nodeBase + col, node1 = nodeBase + 16 + col;

    f32x4 acc[2][8];
#pragma unroll
    for (int nb = 0; nb < 2; nb++)
#pragma unroll
        for (int f = 0; f < 8; f++) acc[nb][f] = (f32x4)0.f;

    for (int s = 0; s < 4; s++) {
        int k0 = s * 32 + quad * 8;
        float v0[8], v1[8];
#pragma unroll
        for (int j = 0; j < 8; j++) { v0[j] = 0.f; v1[j] = 0.f; }
        if (node0 < N) {
            float4 a = *(const float4*)&A[(size_t)node0 * 128 + k0];
            float4 b = *(const float4*)&A[(size_t)node0 * 128 + k0 + 4];
            v0[0] = a.x; v0[1] = a.y; v0[2] = a.z; v0[3] = a.w;
            v0[4] = b.x; v0[5] = b.y; v0[6] = b.z; v0[7] = b.w;
        }
        if (node1 < N) {
            float4 a = *(const float4*)&A[(size_t)node1 * 128 + k0];
            float4 b = *(const float4*)&A[(size_t)node1 * 128 + k0 + 4];
            v1[0] = a.x; v1[1] = a.y; v1[2] = a.z; v1[3] = a.w;
            v1[4] = b.x; v1[5] = b.y; v1[6] = b.z; v1[7] = b.w;
        }
        bf16x8 bh0, bl0, bh1, bl1;
#pragma unroll
        for (int j = 0; j < 8; j++) {
            ushort h, l;
            split2(v0[j], h, l); bh0[j] = (short)h; bl0[j] = (short)l;
            split2(v1[j], h, l); bh1[j] = (short)h; bl1[j] = (short)l;
        }
#pragma unroll
        for (int f = 0; f < 8; f++) {
            bf16x8 wh = *(const bf16x8*)&Whi_s[f * 16 + col][k0];
            bf16x8 wl = *(const bf16x8*)&Wlo_s[f * 16 + col][k0];
            acc[0][f] = __builtin_amdgcn_mfma_f32_16x16x32_bf16(wh, bh0, acc[0][f], 0, 0, 0);
            acc[1][f] = __builtin_amdgcn_mfma_f32_16x16x32_bf16(wh, bh1, acc[1][f], 0, 0, 0);
            acc[0][f] = __builtin_amdgcn_mfma_f32_16x16x32_bf16(wl, bh0, acc[0][f], 0, 0, 0);
            acc[1][f] = __builtin_amdgcn_mfma_f32_16x16x32_bf16(wl, bh1, acc[1][f], 0, 0, 0);
            acc[0][f] = __builtin_amdgcn_mfma_f32_16x16x32_bf16(wh, bl0, acc[0][f], 0, 0, 0);
            acc[1][f] = __builtin_amdgcn_mfma_f32_16x16x32_bf16(wh, bl1, acc[1][f], 0, 0, 0);
        }
    }
#pragma unroll
    for (int nb = 0; nb < 2; nb++) {
        int node = nodeBase + nb * 16 + col;
        if (node >= N) continue;
        float d = disq[node];
#pragma unroll
        for (int f = 0; f < 8; f++) {
            f32x4 a = acc[nb][f];
            uint2 u;
            u.x = bf16pack(a[0] * d, a[1] * d);
            u.y = bf16pack(a[2] * d, a[3] * d);
            *(uint2*)&Cout[(size_t)node * 64 + f * 8 + quad * 2] = u;
        }
    }
}

// ---- MFMA GEMM, bf16 A (layers 1-4): no A split, 2 MFMAs/frag. ----
template <bool BF16OUT>
__global__ __launch_bounds__(256) void k_gemm_b16A(const unsigned* __restrict__ Ab,
                                                   const ushort* __restrict__ WThi,
                                                   const ushort* __restrict__ WTlo,
                                                   const float* __restrict__ bias,
                                                   const float* __restrict__ disq,
                                                   void* __restrict__ Cout, int N) {
    __shared__ ushort Whi_s[128][136];
    __shared__ ushort Wlo_s[128][136];
    int tid = threadIdx.x;
#pragma unroll
    for (int r = 0; r < 8; r++) {
        int n  = r * 16 + (tid >> 4);
        int kq = (tid & 15) * 8;
        *(uint4*)&Whi_s[n][kq] = *(const uint4*)&WThi[n * 128 + kq];
        *(uint4*)&Wlo_s[n][kq] = *(const uint4*)&WTlo[n * 128 + kq];
    }
    __syncthreads();

    int wv = tid >> 6, ln = tid & 63;
    int quad = ln >> 4, col = ln & 15;
    int nodeBase = blockIdx.x * 128 + wv * 32;
    int node0 = nodeBase + col, node1 = nodeBase + 16 + col;

    f32x4 acc[2][8];
#pragma unroll
    for (int nb = 0; nb < 2; nb++)
#pragma unroll
        for (int f = 0; f < 8; f++) acc[nb][f] = (f32x4)0.f;

    for (int s = 0; s < 4; s++) {
        int k0 = s * 32 + quad * 8;     // element offset
        int kw = s * 16 + quad * 4;     // word offset (2 bf16/word)
        bf16x8 b0 = (bf16x8)(short)0, b1 = (bf16x8)(short)0;
        if (node0 < N) b0 = *(const bf16x8*)&Ab[(size_t)node0 * 64 + kw];
        if (node1 < N) b1 = *(const bf16x8*)&Ab[(size_t)node1 * 64 + kw];
#pragma unroll
        for (int f = 0; f < 8; f++) {
            bf16x8 wh = *(const bf16x8*)&Whi_s[f * 16 + col][k0];
            bf16x8 wl = *(const bf16x8*)&Wlo_s[f * 16 + col][k0];
            acc[0][f] = __builtin_amdgcn_mfma_f32_16x16x32_bf16(wh, b0, acc[0][f], 0, 0, 0);
            acc[1][f] = __builtin_amdgcn_mfma_f32_16x16x32_bf16(wh, b1, acc[1][f], 0, 0, 0);
            acc[0][f] = __builtin_amdgcn_mfma_f32_16x16x32_bf16(wl, b0, acc[0][f], 0, 0, 0);
            acc[1][f] = __builtin_amdgcn_mfma_f32_16x16x32_bf16(wl, b1, acc[1][f], 0, 0, 0);
        }
    }
#pragma unroll
    for (int nb = 0; nb < 2; nb++) {
        int node = nodeBase + nb * 16 + col;
        if (node >= N) continue;
        if (BF16OUT) {
            float d = disq[node];
            unsigned* tb = (unsigned*)Cout;
#pragma unroll
            for (int f = 0; f < 8; f++) {
                f32x4 a = acc[nb][f];
                uint2 u;
                u.x = bf16pack(a[0] * d, a[1] * d);
                u.y = bf16pack(a[2] * d, a[3] * d);
                *(uint2*)&tb[(size_t)node * 64 + f * 8 + quad * 2] = u;
            }
        } else {
            float* C = (float*)Cout;
#pragma unroll
            for (int f = 0; f < 8; f++) {
                int fb = f * 16 + quad * 4;
                float4 bv = *(const float4*)&bias[fb];
                f32x4 a = acc[nb][f];
                float4 o;
                o.x = a[0] + bv.x; o.y = a[1] + bv.y;
                o.z = a[2] + bv.z; o.w = a[3] + bv.w;
                *(float4*)&C[(size_t)node * 128 + fb] = o;
            }
        }
    }
}

// ---- Gather-aggregate: 16-lane quarter owns ONE node, 8-deep pipeline. ----
// 32 outstanding 16B loads per wave (2x the old 4-slot/quarter-split scheme)
// to cover ~900cy memory latency; no cross-lane reduction, full-width store.
__global__ __launch_bounds__(256, 8) void k_aggregate(const unsigned* __restrict__ tb,
                                                      const int* __restrict__ offsets,
                                                      const uint2* __restrict__ edges,
                                                      const float* __restrict__ disq,
                                                      const float* __restrict__ bias,
                                                      unsigned* __restrict__ outb,
                                                      int N, int relu) {
    const int tid = threadIdx.x;
    const int wv = tid >> 6, lane = tid & 63;
    const int q = lane >> 4, li = lane & 15;
    const int node = blockIdx.x * 16 + wv * 4 + q;
    if (node >= N) return;
    const char* tbc = (const char*)tb;

    int e0 = offsets[node], e1 = offsets[node + 1];
    float4 acc0 = make_float4(0.f, 0.f, 0.f, 0.f);
    float4 acc1 = make_float4(0.f, 0.f, 0.f, 0.f);

    float cf[8]; uint4 w[8];
#pragma unroll
    for (int s = 0; s < 8; s++) { cf[s] = 0.f; w[s] = make_uint4(0u, 0u, 0u, 0u); }

#define FETCH(S, II) {                                                     \
        int ii = (II);                                                     \
        if (ii < e1) {                                                     \
            uint2 m = edges[ii];                                           \
            cf[S] = __uint_as_float(m.y);                                  \
            w[S]  = *(const uint4*)(tbc + m.x + (li << 4));                \
        } else cf[S] = 0.f;                                                \
    }
#define CONSUME(S) {                                                       \
        float4 a, b; bf16x8_expand(w[S], a, b);                            \
        float c = cf[S];                                                   \
        acc0.x += c * a.x; acc0.y += c * a.y;                              \
        acc0.z += c * a.z; acc0.w += c * a.w;                              \
        acc1.x += c * b.x; acc1.y += c * b.y;                              \
        acc1.z += c * b.z; acc1.w += c * b.w;                              \
    }

    FETCH(0, e0)     FETCH(1, e0 + 1) FETCH(2, e0 + 2) FETCH(3, e0 + 3)
    FETCH(4, e0 + 4) FETCH(5, e0 + 5) FETCH(6, e0 + 6) FETCH(7, e0 + 7)
    for (int eb = e0 + 8; eb < e1; eb += 8) {
        CONSUME(0) FETCH(0, eb)
        CONSUME(1) FETCH(1, eb + 1)
        CONSUME(2) FETCH(2, eb + 2)
        CONSUME(3) FETCH(3, eb + 3)
        CONSUME(4) FETCH(4, eb + 4)
        CONSUME(5) FETCH(5, eb + 5)
        CONSUME(6) FETCH(6, eb + 6)
        CONSUME(7) FETCH(7, eb + 7)
    }
    CONSUME(0) CONSUME(1) CONSUME(2) CONSUME(3)
    CONSUME(4) CONSUME(5) CONSUME(6) CONSUME(7)
#undef FETCH
#undef CONSUME

    float d = disq[node];
    uint4 sv = *(const uint4*)(tbc + ((size_t)node << 8) + (li << 4));
    float4 ta, tbv;
    bf16x8_expand(sv, ta, tbv);
    float4 b0 = *(const float4*)&bias[li * 8];
    float4 b1 = *(const float4*)&bias[li * 8 + 4];
    float4 o0, o1;
    o0.x = d * (acc0.x + ta.x) + b0.x;
    o0.y = d * (acc0.y + ta.y) + b0.y;
    o0.z = d * (acc0.z + ta.z) + b0.z;
    o0.w = d * (acc0.w + ta.w) + b0.w;
    o1.x = d * (acc1.x + tbv.x) + b1.x;
    o1.y = d * (acc1.y + tbv.y) + b1.y;
    o1.z = d * (acc1.z + tbv.z) + b1.z;
    o1.w = d * (acc1.w + tbv.w) + b1.w;
    if (relu) {
        o0.x = fmaxf(o0.x, 0.f); o0.y = fmaxf(o0.y, 0.f);
        o0.z = fmaxf(o0.z, 0.f); o0.w = fmaxf(o0.w, 0.f);
        o1.x = fmaxf(o1.x, 0.f); o1.y = fmaxf(o1.y, 0.f);
        o1.z = fmaxf(o1.z, 0.f); o1.w = fmaxf(o1.w, 0.f);
    }
    uint4 u;
    u.x = bf16pack(o0.x, o0.y);
    u.y = bf16pack(o0.z, o0.w);
    u.z = bf16pack(o1.x, o1.y);
    u.w = bf16pack(o1.z, o1.w);
    *(uint4*)&outb[(size_t)node * 64 + li * 4] = u;
}

extern "C" void kernel_launch(void* const* d_in, const int* in_sizes, int n_in,
                              void* d_out, int out_size, void* d_ws, size_t ws_size,
                              hipStream_t stream) {
    const float* x    = (const float*)d_in[0];
    const int*   ei   = (const int*)d_in[1];
    const float* ew   = (const float*)d_in[2];
    const float* Wc[4] = {(const float*)d_in[3], (const float*)d_in[5],
                          (const float*)d_in[7], (const float*)d_in[9]};
    const float* bc[4] = {(const float*)d_in[4], (const float*)d_in[6],
                          (const float*)d_in[8], (const float*)d_in[10]};
    const float* Wout = (const float*)d_in[11];
    const float* bout = (const float*)d_in[12];

    const int N = in_sizes[0] / 128;
    const int E = in_sizes[2];
    const int* row = ei;
    const int* col = ei + E;

    const int K     = (N + 255) >> 8;
    const int B1    = 256;
    const int chunk = (E + B1 - 1) / B1;
    const int nScan = K * B1;

    size_t off = 0;
    char* base = (char*)d_ws;
    auto alloc = [&](size_t bytes) -> void* {
        void* p = base + off;
        off += (bytes + 255) & ~(size_t)255;
        return p;
    };
    float*    disq     = (float*)alloc((size_t)N * 4);
    int*      offsets  = (int*)alloc((size_t)(N + 1) * 4);
    int*      hist     = (int*)alloc((size_t)nScan * 4);
    int*      binBase  = (int*)alloc((size_t)(nScan + 1) * 4);
    int*      partials = (int*)alloc(1024 * 4);
    int*      blockOff = (int*)alloc(1024 * 4);
    ushort*   WThi     = (ushort*)alloc((size_t)5 * 16384 * 2);
    ushort*   WTlo     = (ushort*)alloc((size_t)5 * 16384 * 2);
    uint2*    etmp     = (uint2*)alloc((size_t)E * 8);
    uint2*    edges    = (uint2*)alloc((size_t)E * 8);
    unsigned* hb       = (unsigned*)alloc((size_t)N * 64 * 4);   // bf16 h
    unsigned* tb       = (unsigned*)alloc((size_t)N * 64 * 4);   // bf16 t'

    const int BG  = (N + 127) / 128;
    const int BA  = (N + 15) / 16;
    const int NBs = (nScan + SCAN_CHUNK - 1) / SCAN_CHUNK;

    // Weight prep + CSR build (no global atomics)
    k_prepw<<<5, 256, 0, stream>>>(Wc[0], Wc[1], Wc[2], Wc[3], Wout, WThi, WTlo);
    k_hist<<<B1, 256, 0, stream>>>(col, hist, E, K, B1, chunk);
    k_scan_part<<<NBs, 256, 0, stream>>>(hist, partials, nScan);
    k_scan_top<<<1, 1024, 0, stream>>>(partials, blockOff, binBase, NBs, nScan);
    k_scan_out<<<NBs, 256, 0, stream>>>(hist, blockOff, binBase, nScan);
    k_scatter<<<B1, 256, 0, stream>>>(row, col, ew, binBase, etmp, E, K, B1, chunk);
    k_bucket<<<K, 256, 0, stream>>>(etmp, binBase, edges, offsets, disq, N, K, B1);

    // Layers (GEMM -> aggregate); h kept in bf16 from layer 1 on
    k_gemm_f32A<<<BG, 256, 0, stream>>>(x, WThi, WTlo, disq, tb, N);
    k_aggregate<<<BA, 256, 0, stream>>>(tb, offsets, edges, disq, bc[0], hb, N, 1);
    k_gemm_b16A<true><<<BG, 256, 0, stream>>>(hb, WThi + 16384, WTlo + 16384, nullptr, disq, tb, N);
    k_aggregate<<<BA, 256, 0, stream>>>(tb, offsets, edges, disq, bc[1], hb, N, 1);
    k_gemm_b16A<true><<<BG, 256, 0, stream>>>(hb, WThi + 32768, WTlo + 32768, nullptr, disq, tb, N);
    k_aggregate<<<BA, 256, 0, stream>>>(tb, offsets, edges, disq, bc[2], hb, N, 1);
    k_gemm_b16A<true><<<BG, 256, 0, stream>>>(hb, WThi + 49152, WTlo + 49152, nullptr, disq, tb, N);
    k_aggregate<<<BA, 256, 0, stream>>>(tb, offsets, edges, disq, bc[3], hb, N, 0);
    // Output projection (fp32 + bias)
    k_gemm_b16A<false><<<BG, 256, 0, stream>>>(hb, WThi + 65536, WTlo + 65536, bout, nullptr, d_out, N);
}

// Round 4
// 580.517 us; speedup vs baseline: 3.6465x; 3.6465x over previous
//
#include <hip/hip_runtime.h>

// ---------------------------------------------------------------------------
// GCN: 4x GCNConv(128->128) + final linear.
// CSR build with zero global atomics (two-level counting sort).
// Per layer: MFMA GEMM t' = disq*(h@W), then CSR gather-aggregate.
// Aggregate: 16-lane quarter OWNS one node; 8-deep rotating gather pipeline
// with META PREFETCHED ONE ROUND AHEAD (decouples meta latency from gather
// critical path). __launch_bounds__(256,4): round-3's (256,8) capped VGPR at
// 64 and spilled the pipeline arrays to scratch (WRITE_SIZE 25MB -> 1.26GB).
// ---------------------------------------------------------------------------

#define SCAN_CHUNK 1024
#define NBUCK_MAX  512
#define BCAP       6144

typedef __attribute__((ext_vector_type(8))) short bf16x8;
typedef __attribute__((ext_vector_type(4))) float f32x4;

__device__ inline unsigned bf16pack(float a, float b) {  // RTNE pack, a->low
    unsigned ua = __float_as_uint(a);
    unsigned ub = __float_as_uint(b);
    ua = (ua + 0x7fffu + ((ua >> 16) & 1u)) >> 16;
    ub = (ub + 0x7fffu + ((ub >> 16) & 1u)) & 0xffff0000u;
    return ua | ub;
}

__device__ inline void split2(float x, ushort& hi, ushort& lo) {
    unsigned u = __float_as_uint(x);
    unsigned r = (u + 0x7fffu + ((u >> 16) & 1u)) & 0xffff0000u;
    hi = (ushort)(r >> 16);
    float rem = x - __uint_as_float(r);
    unsigned u2 = __float_as_uint(rem);
    lo = (ushort)((u2 + 0x7fffu + ((u2 >> 16) & 1u)) >> 16);
}

__device__ inline void bf16x8_expand(uint4 w, float4& a, float4& b) {
    a.x = __uint_as_float(w.x << 16);
    a.y = __uint_as_float(w.x & 0xffff0000u);
    a.z = __uint_as_float(w.y << 16);
    a.w = __uint_as_float(w.y & 0xffff0000u);
    b.x = __uint_as_float(w.z << 16);
    b.y = __uint_as_float(w.z & 0xffff0000u);
    b.z = __uint_as_float(w.w << 16);
    b.w = __uint_as_float(w.w & 0xffff0000u);
}

// ---- W prep: transpose + hi/lo bf16 split of 5 weight matrices ----
__global__ __launch_bounds__(256) void k_prepw(const float* W0, const float* W1,
                                               const float* W2, const float* W3,
                                               const float* W4,
                                               ushort* __restrict__ hiO,
                                               ushort* __restrict__ loO) {
    const float* W = (blockIdx.x == 0) ? W0 : (blockIdx.x == 1) ? W1 :
                     (blockIdx.x == 2) ? W2 : (blockIdx.x == 3) ? W3 : W4;
    ushort* h = hiO + (size_t)blockIdx.x * 16384;
    ushort* l = loO + (size_t)blockIdx.x * 16384;
    for (int idx = threadIdx.x; idx < 4096; idx += 256) {
        int n  = idx >> 5;
        int kq = (idx & 31) * 4;
        ushort hs[4], ls[4];
#pragma unroll
        for (int j = 0; j < 4; j++) split2(W[(kq + j) * 128 + n], hs[j], ls[j]);
        *(uint2*)&h[n * 128 + kq] =
            make_uint2(hs[0] | ((unsigned)hs[1] << 16), hs[2] | ((unsigned)hs[3] << 16));
        *(uint2*)&l[n * 128 + kq] =
            make_uint2(ls[0] | ((unsigned)ls[1] << 16), ls[2] | ((unsigned)ls[3] << 16));
    }
}

// ---- Level-1 pass A: per-block bucket histogram. hist laid out [K][B1]. ----
__global__ __launch_bounds__(256) void k_hist(const int* __restrict__ col,
                                              int* __restrict__ hist,
                                              int E, int K, int B1, int chunk) {
    __shared__ int cnt[NBUCK_MAX];
    int b = blockIdx.x, t = threadIdx.x;
    for (int k = t; k < K; k += 256) cnt[k] = 0;
    __syncthreads();
    int e0 = b * chunk, e1 = min(e0 + chunk, E);
    for (int e = e0 + t; e < e1; e += 256) atomicAdd(&cnt[col[e] >> 8], 1);
    __syncthreads();
    for (int k = t; k < K; k += 256) hist[k * B1 + b] = cnt[k];
}

// ---- 3-phase multi-block exclusive scan ----
__global__ __launch_bounds__(256) void k_scan_part(const int* __restrict__ count,
                                                   int* __restrict__ partials, int n) {
    __shared__ int red[256];
    int t = threadIdx.x;
    int base = blockIdx.x * SCAN_CHUNK + t * 4;
    int s = 0;
#pragma unroll
    for (int j = 0; j < 4; j++) {
        int i = base + j;
        if (i < n) s += count[i];
    }
    red[t] = s;
    __syncthreads();
    for (int off = 128; off > 0; off >>= 1) {
        if (t < off) red[t] += red[t + off];
        __syncthreads();
    }
    if (t == 0) partials[blockIdx.x] = red[0];
}

__global__ __launch_bounds__(1024) void k_scan_top(const int* __restrict__ partials,
                                                   int* __restrict__ blockOff,
                                                   int* __restrict__ result,
                                                   int nb, int n) {
    __shared__ int sums[1024];
    int t = threadIdx.x;
    int v = (t < nb) ? partials[t] : 0;
    sums[t] = v;
    __syncthreads();
    for (int off = 1; off < 1024; off <<= 1) {
        int u = (t >= off) ? sums[t - off] : 0;
        __syncthreads();
        sums[t] += u;
        __syncthreads();
    }
    if (t < nb) blockOff[t] = sums[t] - v;
    if (t == nb - 1) result[n] = sums[t];
}

__global__ __launch_bounds__(256) void k_scan_out(const int* __restrict__ count,
                                                  const int* __restrict__ blockOff,
                                                  int* __restrict__ result, int n) {
    __shared__ int sums[256];
    int t = threadIdx.x;
    int base = blockIdx.x * SCAN_CHUNK + t * 4;
    int c[4]; int s = 0;
#pragma unroll
    for (int j = 0; j < 4; j++) {
        int i = base + j;
        c[j] = (i < n) ? count[i] : 0;
        s += c[j];
    }
    sums[t] = s;
    __syncthreads();
    for (int off = 1; off < 256; off <<= 1) {
        int u = (t >= off) ? sums[t - off] : 0;
        __syncthreads();
        sums[t] += u;
        __syncthreads();
    }
    int run = blockOff[blockIdx.x] + sums[t] - s;
#pragma unroll
    for (int j = 0; j < 4; j++) {
        int i = base + j;
        if (i < n) result[i] = run;
        run += c[j];
    }
}

// ---- Level-1 pass B: scatter edges into bucket-grouped order. ----
__global__ __launch_bounds__(256) void k_scatter(const int* __restrict__ row,
                                                 const int* __restrict__ col,
                                                 const float* __restrict__ ew,
                                                 const int* __restrict__ binBase,
                                                 uint2* __restrict__ etmp,
                                                 int E, int K, int B1, int chunk) {
    __shared__ int cur[NBUCK_MAX];
    int b = blockIdx.x, t = threadIdx.x;
    for (int k = t; k < K; k += 256) cur[k] = binBase[k * B1 + b];
    __syncthreads();
    int e0 = b * chunk, e1 = min(e0 + chunk, E);
    for (int e = e0 + t; e < e1; e += 256) {
        int c = col[e];
        int k = c >> 8;
        int pos = atomicAdd(&cur[k], 1);
        etmp[pos] = make_uint2((unsigned)row[e] | ((unsigned)(c & 255) << 24),
                               __float_as_uint(ew[e]));
    }
}

// ---- Level-2: per-bucket in-LDS counting sort; emit edges/offsets/disq. ----
// edges[].x = src * 256 (pre-multiplied byte offset into the bf16 t' matrix).
__global__ __launch_bounds__(256) void k_bucket(const uint2* __restrict__ etmp,
                                                const int* __restrict__ binBase,
                                                uint2* __restrict__ edges,
                                                int* __restrict__ offsets,
                                                float* __restrict__ disq,
                                                int N, int K, int B1) {
    __shared__ unsigned ls[BCAP];
    __shared__ unsigned lw[BCAP];
    __shared__ int   cnt[256];
    __shared__ float sew[256];
    __shared__ int   excl[257];
    int k = blockIdx.x, t = threadIdx.x;
    int bStart = binBase[k * B1];
    int bEnd   = binBase[(k + 1) * B1];
    int size   = bEnd - bStart;
    cnt[t] = 0; sew[t] = 0.f;
    __syncthreads();
    for (int i = t; i < size && i < BCAP; i += 256) {
        uint2 m = etmp[bStart + i];
        ls[i] = m.x; lw[i] = m.y;
        int j = m.x >> 24;
        atomicAdd(&cnt[j], 1);
        atomicAdd(&sew[j], __uint_as_float(m.y));
    }
    __syncthreads();
    excl[t + 1] = cnt[t];
    if (t == 0) excl[0] = 0;
    __syncthreads();
    for (int off = 1; off < 256; off <<= 1) {
        int add = (t + 1 > off) ? excl[t + 1 - off] : 0;
        __syncthreads();
        excl[t + 1] += add;
        __syncthreads();
    }
    int node = (k << 8) + t;
    if (node < N) {
        offsets[node] = bStart + excl[t];
        disq[node]    = rsqrtf(1.0f + sew[t]);
    }
    if (k == K - 1 && t == 0) offsets[N] = bEnd;
    cnt[t] = excl[t];
    __syncthreads();
    for (int i = t; i < size && i < BCAP; i += 256) {
        unsigned s = ls[i];
        int j = s >> 24;
        int pos = atomicAdd(&cnt[j], 1);
        edges[bStart + pos] = make_uint2((s & 0x00FFFFFFu) << 8, lw[i]);
    }
}

// ---- MFMA GEMM, fp32 A (layer 0 only): split A hi/lo, 3 MFMAs/frag. ----
// D = W^T * h^T; C/D col=node, row=feature quad -> packed bf16 stores.
__global__ __launch_bounds__(256) void k_gemm_f32A(const float* __restrict__ A,
                                                   const ushort* __restrict__ WThi,
                                                   const ushort* __restrict__ WTlo,
                                                   const float* __restrict__ disq,
                                                   unsigned* __restrict__ Cout, int N) {
    __shared__ ushort Whi_s[128][136];
    __shared__ ushort Wlo_s[128][136];
    int tid = threadIdx.x;
#pragma unroll
    for (int r = 0; r < 8; r++) {
        int n  = r * 16 + (tid >> 4);
        int kq = (tid & 15) * 8;
        *(uint4*)&Whi_s[n][kq] = *(const uint4*)&WThi[n * 128 + kq];
        *(uint4*)&Wlo_s[n][kq] = *(const uint4*)&WTlo[n * 128 + kq];
    }
    __syncthreads();

    int wv = tid >> 6, ln = tid & 63;
    int quad = ln >> 4, col = ln & 15;
    int nodeBase = blockIdx.x * 128 + wv * 32;
    int node0 = nodeBase + col, node1 = nodeBase + 16 + col;

    f32x4 acc[2][8];
#pragma unroll
    for (int nb = 0; nb < 2; nb++)
#pragma unroll
        for (int f = 0; f < 8; f++) acc[nb][f] = (f32x4)0.f;

    for (int s = 0; s < 4; s++) {
        int k0 = s * 32 + quad * 8;
        float v0[8], v1[8];
#pragma unroll
        for (int j = 0; j < 8; j++) { v0[j] = 0.f; v1[j] = 0.f; }
        if (node0 < N) {
            float4 a = *(const float4*)&A[(size_t)node0 * 128 + k0];
            float4 b = *(const float4*)&A[(size_t)node0 * 128 + k0 + 4];
            v0[0] = a.x; v0[1] = a.y; v0[2] = a.z; v0[3] = a.w;
            v0[4] = b.x; v0[5] = b.y; v0[6] = b.z; v0[7] = b.w;
        }
        if (node1 < N) {
            float4 a = *(const float4*)&A[(size_t)node1 * 128 + k0];
            float4 b = *(const float4*)&A[(size_t)node1 * 128 + k0 + 4];
            v1[0] = a.x; v1[1] = a.y; v1[2] = a.z; v1[3] = a.w;
            v1[4] = b.x; v1[5] = b.y; v1[6] = b.z; v1[7] = b.w;
        }
        bf16x8 bh0, bl0, bh1, bl1;
#pragma unroll
        for (int j = 0; j < 8; j++) {
            ushort h, l;
            split2(v0[j], h, l); bh0[j] = (short)h; bl0[j] = (short)l;
            split2(v1[j], h, l); bh1[j] = (short)h; bl1[j] = (short)l;
        }
#pragma unroll
        for (int f = 0; f < 8; f++) {
            bf16x8 wh = *(const bf16x8*)&Whi_s[f * 16 + col][k0];
            bf16x8 wl = *(const bf16x8*)&Wlo_s[f * 16 + col][k0];
            acc[0][f] = __builtin_amdgcn_mfma_f32_16x16x32_bf16(wh, bh0, acc[0][f], 0, 0, 0);
            acc[1][f] = __builtin_amdgcn_mfma_f32_16x16x32_bf16(wh, bh1, acc[1][f], 0, 0, 0);
            acc[0][f] = __builtin_amdgcn_mfma_f32_16x16x32_bf16(wl, bh0, acc[0][f], 0, 0, 0);
            acc[1][f] = __builtin_amdgcn_mfma_f32_16x16x32_bf16(wl, bh1, acc[1][f], 0, 0, 0);
            acc[0][f] = __builtin_amdgcn_mfma_f32_16x16x32_bf16(wh, bl0, acc[0][f], 0, 0, 0);
            acc[1][f] = __builtin_amdgcn_mfma_f32_16x16x32_bf16(wh, bl1, acc[1][f], 0, 0, 0);
        }
    }
#pragma unroll
    for (int nb = 0; nb < 2; nb++) {
        int node = nodeBase + nb * 16 + col;
        if (node >= N) continue;
        float d = disq[node];
#pragma unroll
        for (int f = 0; f < 8; f++) {
            f32x4 a = acc[nb][f];
            uint2 u;
            u.x = bf16pack(a[0] * d, a[1] * d);
            u.y = bf16pack(a[2] * d, a[3] * d);
            *(uint2*)&Cout[(size_t)node * 64 + f * 8 + quad * 2] = u;
        }
    }
}

// ---- MFMA GEMM, bf16 A (layers 1-4): no A split, 2 MFMAs/frag. ----
template <bool BF16OUT>
__global__ __launch_bounds__(256) void k_gemm_b16A(const unsigned* __restrict__ Ab,
                                                   const ushort* __restrict__ WThi,
                                                   const ushort* __restrict__ WTlo,
                                                   const float* __restrict__ bias,
                                                   const float* __restrict__ disq,
                                                   void* __restrict__ Cout, int N) {
    __shared__ ushort Whi_s[128][136];
    __shared__ ushort Wlo_s[128][136];
    int tid = threadIdx.x;
#pragma unroll
    for (int r = 0; r < 8; r++) {
        int n  = r * 16 + (tid >> 4);
        int kq = (tid & 15) * 8;
        *(uint4*)&Whi_s[n][kq] = *(const uint4*)&WThi[n * 128 + kq];
        *(uint4*)&Wlo_s[n][kq] = *(const uint4*)&WTlo[n * 128 + kq];
    }
    __syncthreads();

    int wv = tid >> 6, ln = tid & 63;
    int quad = ln >> 4, col = ln & 15;
    int nodeBase = blockIdx.x * 128 + wv * 32;
    int node0 = nodeBase + col, node1 = nodeBase + 16 + col;

    f32x4 acc[2][8];
#pragma unroll
    for (int nb = 0; nb < 2; nb++)
#pragma unroll
        for (int f = 0; f < 8; f++) acc[nb][f] = (f32x4)0.f;

    for (int s = 0; s < 4; s++) {
        int k0 = s * 32 + quad * 8;     // element offset
        int kw = s * 16 + quad * 4;     // word offset (2 bf16/word)
        bf16x8 b0 = (bf16x8)(short)0, b1 = (bf16x8)(short)0;
        if (node0 < N) b0 = *(const bf16x8*)&Ab[(size_t)node0 * 64 + kw];
        if (node1 < N) b1 = *(const bf16x8*)&Ab[(size_t)node1 * 64 + kw];
#pragma unroll
        for (int f = 0; f < 8; f++) {
            bf16x8 wh = *(const bf16x8*)&Whi_s[f * 16 + col][k0];
            bf16x8 wl = *(const bf16x8*)&Wlo_s[f * 16 + col][k0];
            acc[0][f] = __builtin_amdgcn_mfma_f32_16x16x32_bf16(wh, b0, acc[0][f], 0, 0, 0);
            acc[1][f] = __builtin_amdgcn_mfma_f32_16x16x32_bf16(wh, b1, acc[1][f], 0, 0, 0);
            acc[0][f] = __builtin_amdgcn_mfma_f32_16x16x32_bf16(wl, b0, acc[0][f], 0, 0, 0);
            acc[1][f] = __builtin_amdgcn_mfma_f32_16x16x32_bf16(wl, b1, acc[1][f], 0, 0, 0);
        }
    }
#pragma unroll
    for (int nb = 0; nb < 2; nb++) {
        int node = nodeBase + nb * 16 + col;
        if (node >= N) continue;
        if (BF16OUT) {
            float d = disq[node];
            unsigned* tb = (unsigned*)Cout;
#pragma unroll
            for (int f = 0; f < 8; f++) {
                f32x4 a = acc[nb][f];
                uint2 u;
                u.x = bf16pack(a[0] * d, a[1] * d);
                u.y = bf16pack(a[2] * d, a[3] * d);
                *(uint2*)&tb[(size_t)node * 64 + f * 8 + quad * 2] = u;
            }
        } else {
            float* C = (float*)Cout;
#pragma unroll
            for (int f = 0; f < 8; f++) {
                int fb = f * 16 + quad * 4;
                float4 bv = *(const float4*)&bias[fb];
                f32x4 a = acc[nb][f];
                float4 o;
                o.x = a[0] + bv.x; o.y = a[1] + bv.y;
                o.z = a[2] + bv.z; o.w = a[3] + bv.w;
                *(float4*)&C[(size_t)node * 128 + fb] = o;
            }
        }
    }
}

// ---- Gather-aggregate: 16-lane quarter owns ONE node, 8-deep pipeline, ----
// meta prefetched one round ahead. launch_bounds(256,4): 128-VGPR cap, no
// spill (round 3's (256,8) spilled the pipeline arrays -> 1.26GB scratch).
__global__ __launch_bounds__(256, 4) void k_aggregate(const unsigned* __restrict__ tb,
                                                      const int* __restrict__ offsets,
                                                      const uint2* __restrict__ edges,
                                                      const float* __restrict__ disq,
                                                      const float* __restrict__ bias,
                                                      unsigned* __restrict__ outb,
                                                      int N, int relu) {
    const int tid = threadIdx.x;
    const int wv = tid >> 6, lane = tid & 63;
    const int q = lane >> 4, li = lane & 15;
    const int node = blockIdx.x * 16 + wv * 4 + q;
    if (node >= N) return;
    const char* tbc = (const char*)tb;

    int e0 = offsets[node], e1 = offsets[node + 1];
    float4 acc0 = make_float4(0.f, 0.f, 0.f, 0.f);
    float4 acc1 = make_float4(0.f, 0.f, 0.f, 0.f);

    uint2 md[8]; float cf[8]; uint4 w[8];

#define META(S, II) {                                                      \
        int ii = (II);                                                     \
        md[S] = (ii < e1) ? edges[ii] : make_uint2(0u, 0u);                \
    }
#define GATHER(S) {                                                        \
        cf[S] = __uint_as_float(md[S].y);                                  \
        w[S]  = *(const uint4*)(tbc + md[S].x + (li << 4));                \
    }
#define CONSUME(S) {                                                       \
        float4 a, b; bf16x8_expand(w[S], a, b);                            \
        float c = cf[S];                                                   \
        acc0.x += c * a.x; acc0.y += c * a.y;                              \
        acc0.z += c * a.z; acc0.w += c * a.w;                              \
        acc1.x += c * b.x; acc1.y += c * b.y;                              \
        acc1.z += c * b.z; acc1.w += c * b.w;                              \
    }

    // prologue: meta+gather for round 0, meta for round 1
    META(0, e0)     META(1, e0 + 1) META(2, e0 + 2) META(3, e0 + 3)
    META(4, e0 + 4) META(5, e0 + 5) META(6, e0 + 6) META(7, e0 + 7)
    GATHER(0) GATHER(1) GATHER(2) GATHER(3)
    GATHER(4) GATHER(5) GATHER(6) GATHER(7)
    META(0, e0 + 8)  META(1, e0 + 9)  META(2, e0 + 10) META(3, e0 + 11)
    META(4, e0 + 12) META(5, e0 + 13) META(6, e0 + 14) META(7, e0 + 15)

    // steady state: consume round k-1, gather round k (meta already here),
    // prefetch meta round k+1.
    for (int eb = e0 + 8; eb < e1; eb += 8) {
        CONSUME(0) GATHER(0) META(0, eb + 8)
        CONSUME(1) GATHER(1) META(1, eb + 9)
        CONSUME(2) GATHER(2) META(2, eb + 10)
        CONSUME(3) GATHER(3) META(3, eb + 11)
        CONSUME(4) GATHER(4) META(4, eb + 12)
        CONSUME(5) GATHER(5) META(5, eb + 13)
        CONSUME(6) GATHER(6) META(6, eb + 14)
        CONSUME(7) GATHER(7) META(7, eb + 15)
    }
    CONSUME(0) CONSUME(1) CONSUME(2) CONSUME(3)
    CONSUME(4) CONSUME(5) CONSUME(6) CONSUME(7)
#undef META
#undef GATHER
#undef CONSUME

    float d = disq[node];
    uint4 sv = *(const uint4*)(tbc + ((size_t)node << 8) + (li << 4));
    float4 ta, tbv;
    bf16x8_expand(sv, ta, tbv);
    float4 b0 = *(const float4*)&bias[li * 8];
    float4 b1 = *(const float4*)&bias[li * 8 + 4];
    float4 o0, o1;
    o0.x = d * (acc0.x + ta.x) + b0.x;
    o0.y = d * (acc0.y + ta.y) + b0.y;
    o0.z = d * (acc0.z + ta.z) + b0.z;
    o0.w = d * (acc0.w + ta.w) + b0.w;
    o1.x = d * (acc1.x + tbv.x) + b1.x;
    o1.y = d * (acc1.y + tbv.y) + b1.y;
    o1.z = d * (acc1.z + tbv.z) + b1.z;
    o1.w = d * (acc1.w + tbv.w) + b1.w;
    if (relu) {
        o0.x = fmaxf(o0.x, 0.f); o0.y = fmaxf(o0.y, 0.f);
        o0.z = fmaxf(o0.z, 0.f); o0.w = fmaxf(o0.w, 0.f);
        o1.x = fmaxf(o1.x, 0.f); o1.y = fmaxf(o1.y, 0.f);
        o1.z = fmaxf(o1.z, 0.f); o1.w = fmaxf(o1.w, 0.f);
    }
    uint4 u;
    u.x = bf16pack(o0.x, o0.y);
    u.y = bf16pack(o0.z, o0.w);
    u.z = bf16pack(o1.x, o1.y);
    u.w = bf16pack(o1.z, o1.w);
    *(uint4*)&outb[(size_t)node * 64 + li * 4] = u;
}

extern "C" void kernel_launch(void* const* d_in, const int* in_sizes, int n_in,
                              void* d_out, int out_size, void* d_ws, size_t ws_size,
                              hipStream_t stream) {
    const float* x    = (const float*)d_in[0];
    const int*   ei   = (const int*)d_in[1];
    const float* ew   = (const float*)d_in[2];
    const float* Wc[4] = {(const float*)d_in[3], (const float*)d_in[5],
                          (const float*)d_in[7], (const float*)d_in[9]};
    const float* bc[4] = {(const float*)d_in[4], (const float*)d_in[6],
                          (const float*)d_in[8], (const float*)d_in[10]};
    const float* Wout = (const float*)d_in[11];
    const float* bout = (const float*)d_in[12];

    const int N = in_sizes[0] / 128;
    const int E = in_sizes[2];
    const int* row = ei;
    const int* col = ei + E;

    const int K     = (N + 255) >> 8;
    const int B1    = 256;
    const int chunk = (E + B1 - 1) / B1;
    const int nScan = K * B1;

    size_t off = 0;
    char* base = (char*)d_ws;
    auto alloc = [&](size_t bytes) -> void* {
        void* p = base + off;
        off += (bytes + 255) & ~(size_t)255;
        return p;
    };
    float*    disq     = (float*)alloc((size_t)N * 4);
    int*      offsets  = (int*)alloc((size_t)(N + 1) * 4);
    int*      hist     = (int*)alloc((size_t)nScan * 4);
    int*      binBase  = (int*)alloc((size_t)(nScan + 1) * 4);
    int*      partials = (int*)alloc(1024 * 4);
    int*      blockOff = (int*)alloc(1024 * 4);
    ushort*   WThi     = (ushort*)alloc((size_t)5 * 16384 * 2);
    ushort*   WTlo     = (ushort*)alloc((size_t)5 * 16384 * 2);
    uint2*    etmp     = (uint2*)alloc((size_t)E * 8);
    uint2*    edges    = (uint2*)alloc((size_t)E * 8);
    unsigned* hb       = (unsigned*)alloc((size_t)N * 64 * 4);   // bf16 h
    unsigned* tb       = (unsigned*)alloc((size_t)N * 64 * 4);   // bf16 t'

    const int BG  = (N + 127) / 128;
    const int BA  = (N + 15) / 16;
    const int NBs = (nScan + SCAN_CHUNK - 1) / SCAN_CHUNK;

    // Weight prep + CSR build (no global atomics)
    k_prepw<<<5, 256, 0, stream>>>(Wc[0], Wc[1], Wc[2], Wc[3], Wout, WThi, WTlo);
    k_hist<<<B1, 256, 0, stream>>>(col, hist, E, K, B1, chunk);
    k_scan_part<<<NBs, 256, 0, stream>>>(hist, partials, nScan);
    k_scan_top<<<1, 1024, 0, stream>>>(partials, blockOff, binBase, NBs, nScan);
    k_scan_out<<<NBs, 256, 0, stream>>>(hist, blockOff, binBase, nScan);
    k_scatter<<<B1, 256, 0, stream>>>(row, col, ew, binBase, etmp, E, K, B1, chunk);
    k_bucket<<<K, 256, 0, stream>>>(etmp, binBase, edges, offsets, disq, N, K, B1);

    // Layers (GEMM -> aggregate); h kept in bf16 from layer 1 on
    k_gemm_f32A<<<BG, 256, 0, stream>>>(x, WThi, WTlo, disq, tb, N);
    k_aggregate<<<BA, 256, 0, stream>>>(tb, offsets, edges, disq, bc[0], hb, N, 1);
    k_gemm_b16A<true><<<BG, 256, 0, stream>>>(hb, WThi + 16384, WTlo + 16384, nullptr, disq, tb, N);
    k_aggregate<<<BA, 256, 0, stream>>>(tb, offsets, edges, disq, bc[1], hb, N, 1);
    k_gemm_b16A<true><<<BG, 256, 0, stream>>>(hb, WThi + 32768, WTlo + 32768, nullptr, disq, tb, N);
    k_aggregate<<<BA, 256, 0, stream>>>(tb, offsets, edges, disq, bc[2], hb, N, 1);
    k_gemm_b16A<true><<<BG, 256, 0, stream>>>(hb, WThi + 49152, WTlo + 49152, nullptr, disq, tb, N);
    k_aggregate<<<BA, 256, 0, stream>>>(tb, offsets, edges, disq, bc[3], hb, N, 0);
    // Output projection (fp32 + bias)
    k_gemm_b16A<false><<<BG, 256, 0, stream>>>(hb, WThi + 65536, WTlo + 65536, bout, nullptr, d_out, N);
}